// Round 1
// baseline (136.162 us; speedup 1.0000x reference)
//
#include <hip/hip_runtime.h>
#include <math.h>

#define NUM_CLASSES 80
#define M_GT 128

__global__ void yolo_init_acc(double* acc) {
    if (threadIdx.x < 3) acc[threadIdx.x] = 0.0;
}

__global__ __launch_bounds__(256) void yolo_main_kernel(
    const float* __restrict__ box_preds,   // [B,N,4]
    const float* __restrict__ cls_preds,   // [B,N,C]
    const float* __restrict__ gt_boxes,    // [B,M,4]
    const int*   __restrict__ gt_labels,   // [B,M]
    double* __restrict__ acc,              // [3]: box_l, cls_l, npos
    int N)
{
    const int b = blockIdx.y;
    const int n = blockIdx.x * blockDim.x + threadIdx.x;

    __shared__ float gx1[M_GT], gy1[M_GT], gx2[M_GT], gy2[M_GT], garea[M_GT];
    __shared__ int   glbl[M_GT];

    for (int m = threadIdx.x; m < M_GT; m += blockDim.x) {
        float4 g = reinterpret_cast<const float4*>(gt_boxes + (size_t)b * M_GT * 4)[m];
        gx1[m] = g.x; gy1[m] = g.y; gx2[m] = g.z; gy2[m] = g.w;
        garea[m] = (g.z - g.x) * (g.w - g.y);
        glbl[m] = gt_labels[b * M_GT + m];
    }
    __syncthreads();

    float box_l = 0.f, cls_l = 0.f, npos = 0.f;

    if (n < N) {
        float4 p = reinterpret_cast<const float4*>(box_preds + (size_t)b * N * 4)[n];
        const float a1 = (p.z - p.x) * (p.w - p.y);

        float best = -1e30f;
        int bidx = 0;
        #pragma unroll 4
        for (int m = 0; m < M_GT; ++m) {
            float ltx = fmaxf(p.x, gx1[m]);
            float lty = fmaxf(p.y, gy1[m]);
            float rbx = fminf(p.z, gx2[m]);
            float rby = fminf(p.w, gy2[m]);
            float w = fmaxf(rbx - ltx, 0.f);
            float h = fmaxf(rby - lty, 0.f);
            float inter = w * h;
            float uni = a1 + garea[m] - inter;
            float iou = inter / uni;
            float ex = fmaxf(fmaxf(p.z, gx2[m]) - fminf(p.x, gx1[m]), 0.f);
            float ey = fmaxf(fmaxf(p.w, gy2[m]) - fminf(p.y, gy1[m]), 0.f);
            float ae = ex * ey;
            float giou = iou - (ae - uni) / ae;
            if (giou > best) { best = giou; bidx = m; }  // strict > keeps first idx (jnp.argmax)
        }

        if (best > 0.3f) {
            npos = 1.f;
            box_l = 1.f - best;   // elementwise giou(pred, matched_gt) == best (identical arithmetic)
            const int lbl = glbl[bidx];
            const float* xrow = cls_preds + ((size_t)b * N + n) * NUM_CLASSES;
            float cl = 0.f;
            #pragma unroll 4
            for (int c = 0; c < NUM_CLASSES; ++c) {
                float x = xrow[c];
                bool is_t = (c == lbl);
                float ax = fabsf(x);
                float l1p = log1pf(expf(-ax));                 // stable BCE tail
                float ce = fmaxf(x, 0.f) - (is_t ? x : 0.f) + l1p;
                float pr = 1.f / (1.f + expf(-x));
                float pt = is_t ? pr : (1.f - pr);
                float at = is_t ? 0.25f : 0.75f;
                float om = 1.f - pt;
                cl += at * om * om * ce;
            }
            cls_l = cl;
        }
    }

    // wave (64-lane) reduction
    #pragma unroll
    for (int off = 32; off > 0; off >>= 1) {
        box_l += __shfl_down(box_l, off);
        cls_l += __shfl_down(cls_l, off);
        npos  += __shfl_down(npos,  off);
    }

    __shared__ float red[4][3];
    const int wave = threadIdx.x >> 6;
    const int lane = threadIdx.x & 63;
    if (lane == 0) { red[wave][0] = box_l; red[wave][1] = cls_l; red[wave][2] = npos; }
    __syncthreads();
    if (threadIdx.x == 0) {
        float b0 = 0.f, c0 = 0.f, p0 = 0.f;
        for (int w = 0; w < 4; ++w) { b0 += red[w][0]; c0 += red[w][1]; p0 += red[w][2]; }
        atomicAdd(&acc[0], (double)b0);
        atomicAdd(&acc[1], (double)c0);
        atomicAdd(&acc[2], (double)p0);
    }
}

__global__ void yolo_finalize(const double* __restrict__ acc, float* __restrict__ out) {
    if (threadIdx.x == 0) {
        double loss = (5.0 * acc[0] + acc[1]) / fmax(acc[2], 1.0);
        out[0] = (float)loss;
    }
}

extern "C" void kernel_launch(void* const* d_in, const int* in_sizes, int n_in,
                              void* d_out, int out_size, void* d_ws, size_t ws_size,
                              hipStream_t stream) {
    const float* box_preds = (const float*)d_in[0];
    const float* cls_preds = (const float*)d_in[1];
    const float* gt_boxes  = (const float*)d_in[2];
    const int*   gt_labels = (const int*)d_in[3];

    const int B = in_sizes[3] / M_GT;            // gt_labels is [B,M]
    const int N = in_sizes[0] / (4 * B);         // box_preds is [B,N,4]

    double* acc = (double*)d_ws;
    float*  out = (float*)d_out;

    yolo_init_acc<<<1, 64, 0, stream>>>(acc);

    dim3 grid((N + 255) / 256, B);
    yolo_main_kernel<<<grid, 256, 0, stream>>>(box_preds, cls_preds, gt_boxes, gt_labels, acc, N);

    yolo_finalize<<<1, 64, 0, stream>>>(acc, out);
}

// Round 2
// 120.233 us; speedup vs baseline: 1.1325x; 1.1325x over previous
//
#include <hip/hip_runtime.h>
#include <math.h>

#define NUM_CLASSES 80
#define M_GT 128

__global__ void yolo_init_acc(double* acc) {
    if (threadIdx.x < 3) acc[threadIdx.x] = 0.0;
}

__global__ __launch_bounds__(256) void yolo_main_kernel(
    const float* __restrict__ box_preds,   // [B,N,4]
    const float* __restrict__ cls_preds,   // [B,N,C]
    const float* __restrict__ gt_boxes,    // [B,M,4]
    const int*   __restrict__ gt_labels,   // [B,M]
    double* __restrict__ acc,              // [3]: box_l, cls_l, npos
    int N)
{
    const int b = blockIdx.y;
    const int n = blockIdx.x * blockDim.x + threadIdx.x;

    // Packed GT data: gta = {x1,y1,x2,y2}, gtb = {wx,wy,area,label_bits}
    __shared__ float4 gta[M_GT];
    __shared__ float4 gtb[M_GT];

    for (int m = threadIdx.x; m < M_GT; m += blockDim.x) {
        float4 g = reinterpret_cast<const float4*>(gt_boxes + (size_t)b * M_GT * 4)[m];
        gta[m] = g;
        float wx = g.z - g.x, wy = g.w - g.y;
        gtb[m] = make_float4(wx, wy, wx * wy, __int_as_float(gt_labels[b * M_GT + m]));
    }
    __syncthreads();

    float box_l = 0.f, cls_l = 0.f, npos = 0.f;

    if (n < N) {
        float4 p = reinterpret_cast<const float4*>(box_preds + (size_t)b * N * 4)[n];
        const float pw = p.z - p.x;
        const float ph = p.w - p.y;
        const float a1 = pw * ph;

        float best = -1e30f;
        int bidx = 0;
        #pragma unroll 16
        for (int m = 0; m < M_GT; ++m) {
            float4 g = gta[m];
            float4 q = gtb[m];
            // unclamped intersection extents
            float dx = fminf(p.z, g.z) - fmaxf(p.x, g.x);
            float dy = fminf(p.w, g.w) - fmaxf(p.y, g.y);
            float w = fmaxf(dx, 0.f);
            float h = fmaxf(dy, 0.f);
            // enclosure extents via max(a,b)+min(a,b)=a+b identity (always >= 0)
            float ex = (pw + q.x) - dx;
            float ey = (ph + q.y) - dy;
            float inter = w * h;
            float uni = (a1 + q.z) - inter;
            float ae = ex * ey;
            // giou = inter/uni + uni/ae - 1   (== iou - (ae-uni)/ae)
            float giou = fmaf(uni, __builtin_amdgcn_rcpf(ae),
                              fmaf(inter, __builtin_amdgcn_rcpf(uni), -1.f));
            if (giou > best) { best = giou; bidx = m; }  // strict > keeps first idx
        }

        if (best > 0.3f) {
            npos = 1.f;
            box_l = 1.f - best;   // elementwise giou(pred, matched_gt) == best
            const int lbl = __float_as_int(gtb[bidx].w);
            const float* xrow = cls_preds + ((size_t)b * N + n) * NUM_CLASSES;
            float cl = 0.f;
            #pragma unroll 5
            for (int c4 = 0; c4 < NUM_CLASSES / 4; ++c4) {
                float4 xv = reinterpret_cast<const float4*>(xrow)[c4];
                const float xs[4] = {xv.x, xv.y, xv.z, xv.w};
                #pragma unroll
                for (int j = 0; j < 4; ++j) {
                    int c = c4 * 4 + j;
                    float x = xs[j];
                    bool is_t = (c == lbl);
                    float ax = fabsf(x);
                    float l1p = log1pf(expf(-ax));              // stable BCE tail
                    float ce = fmaxf(x, 0.f) - (is_t ? x : 0.f) + l1p;
                    float pr = 1.f / (1.f + expf(-x));
                    float pt = is_t ? pr : (1.f - pr);
                    float at = is_t ? 0.25f : 0.75f;
                    float om = 1.f - pt;
                    cl += at * om * om * ce;
                }
            }
            cls_l = cl;
        }
    }

    // wave (64-lane) reduction
    #pragma unroll
    for (int off = 32; off > 0; off >>= 1) {
        box_l += __shfl_down(box_l, off);
        cls_l += __shfl_down(cls_l, off);
        npos  += __shfl_down(npos,  off);
    }

    __shared__ float red[4][3];
    const int wave = threadIdx.x >> 6;
    const int lane = threadIdx.x & 63;
    if (lane == 0) { red[wave][0] = box_l; red[wave][1] = cls_l; red[wave][2] = npos; }
    __syncthreads();
    if (threadIdx.x == 0) {
        float b0 = 0.f, c0 = 0.f, p0 = 0.f;
        for (int w = 0; w < 4; ++w) { b0 += red[w][0]; c0 += red[w][1]; p0 += red[w][2]; }
        atomicAdd(&acc[0], (double)b0);
        atomicAdd(&acc[1], (double)c0);
        atomicAdd(&acc[2], (double)p0);
    }
}

__global__ void yolo_finalize(const double* __restrict__ acc, float* __restrict__ out) {
    if (threadIdx.x == 0) {
        double loss = (5.0 * acc[0] + acc[1]) / fmax(acc[2], 1.0);
        out[0] = (float)loss;
    }
}

extern "C" void kernel_launch(void* const* d_in, const int* in_sizes, int n_in,
                              void* d_out, int out_size, void* d_ws, size_t ws_size,
                              hipStream_t stream) {
    const float* box_preds = (const float*)d_in[0];
    const float* cls_preds = (const float*)d_in[1];
    const float* gt_boxes  = (const float*)d_in[2];
    const int*   gt_labels = (const int*)d_in[3];

    const int B = in_sizes[3] / M_GT;            // gt_labels is [B,M]
    const int N = in_sizes[0] / (4 * B);         // box_preds is [B,N,4]

    double* acc = (double*)d_ws;
    float*  out = (float*)d_out;

    yolo_init_acc<<<1, 64, 0, stream>>>(acc);

    dim3 grid((N + 255) / 256, B);
    yolo_main_kernel<<<grid, 256, 0, stream>>>(box_preds, cls_preds, gt_boxes, gt_labels, acc, N);

    yolo_finalize<<<1, 64, 0, stream>>>(acc, out);
}

// Round 3
// 87.890 us; speedup vs baseline: 1.5492x; 1.3680x over previous
//
#include <hip/hip_runtime.h>
#include <math.h>

#define NUM_CLASSES 80
#define M_GT 128
#define IOU_THR 0.3f

// d_ws layout: [0,16): double acc[2] (box_l, cls_l); [16,20): int counter; [32+): uint list
__global__ void yolo_init_acc(void* ws) {
    if (threadIdx.x == 0) {
        ((double*)ws)[0] = 0.0;
        ((double*)ws)[1] = 0.0;
        ((int*)ws)[4] = 0;   // counter at byte 16
    }
}

__device__ __forceinline__ float focal_neg(float x) {
    // alpha=0.75 (1-ALPHA), t=0 focal term: 0.75 * p^2 * (max(x,0)+log1p(exp(-|x|)))
    float ax = fabsf(x);
    float e  = __expf(-ax);
    float s  = 1.f + e;
    float r  = __builtin_amdgcn_rcpf(s);
    float l1p = __logf(s);
    float ce0 = fmaxf(x, 0.f) + l1p;
    float pr  = (x >= 0.f) ? r : e * r;      // sigmoid(x)
    return 0.75f * pr * pr * ce0;
}

__device__ __forceinline__ float focal_target_corr(float x) {
    // replace the t=0 term by the t=1 term for the target class
    float ax = fabsf(x);
    float e  = __expf(-ax);
    float s  = 1.f + e;
    float r  = __builtin_amdgcn_rcpf(s);
    float l1p = __logf(s);
    float ce0 = fmaxf(x, 0.f) + l1p;
    float pr  = (x >= 0.f) ? r : e * r;
    float om  = 1.f - pr;
    return 0.25f * om * om * (ce0 - x) - 0.75f * pr * pr * ce0;
}

__global__ __launch_bounds__(256) void yolo_match_kernel(
    const float* __restrict__ box_preds,   // [B,N,4]
    const float* __restrict__ gt_boxes,    // [B,M,4]
    const int*   __restrict__ gt_labels,   // [B,M]
    double* __restrict__ acc,              // acc[0]=box_l
    int* __restrict__ counter,
    unsigned* __restrict__ list,
    int N)
{
    const int b  = blockIdx.y;
    const int n0 = blockIdx.x * 512 + threadIdx.x;   // 2 anchors/thread
    const int n1 = n0 + 256;

    __shared__ float4 gta[M_GT];
    __shared__ int    glbl[M_GT];
    if (threadIdx.x < M_GT) {
        int m = threadIdx.x;
        gta[m]  = reinterpret_cast<const float4*>(gt_boxes + (size_t)b * M_GT * 4)[m];
        glbl[m] = gt_labels[b * M_GT + m];
    }
    __syncthreads();

    const float4* pb = reinterpret_cast<const float4*>(box_preds + (size_t)b * N * 4);
    float4 p0 = pb[n0];
    float4 p1 = pb[n1];
    const float pw0 = p0.z - p0.x, ph0 = p0.w - p0.y, a10 = pw0 * ph0;
    const float pw1 = p1.z - p1.x, ph1 = p1.w - p1.y, a11 = pw1 * ph1;

    float best0 = -1e30f, best1 = -1e30f;
    int   bi0 = 0, bi1 = 0;

    #pragma unroll 8
    for (int m = 0; m < M_GT; ++m) {
        float4 g = gta[m];
        float wx = g.z - g.x, wy = g.w - g.y, a2 = wx * wy;   // shared per m
        // anchor 0
        {
            float dx = fminf(p0.z, g.z) - fmaxf(p0.x, g.x);
            float dy = fminf(p0.w, g.w) - fmaxf(p0.y, g.y);
            float w = fmaxf(dx, 0.f), h = fmaxf(dy, 0.f);
            float inter = w * h;
            float uni = (a10 + a2) - inter;
            float ae = ((pw0 + wx) - dx) * ((ph0 + wy) - dy);
            float gi = fmaf(uni, __builtin_amdgcn_rcpf(ae),
                            fmaf(inter, __builtin_amdgcn_rcpf(uni), -1.f));
            if (gi > best0) { best0 = gi; bi0 = m; }   // strict > keeps first idx
        }
        // anchor 1
        {
            float dx = fminf(p1.z, g.z) - fmaxf(p1.x, g.x);
            float dy = fminf(p1.w, g.w) - fmaxf(p1.y, g.y);
            float w = fmaxf(dx, 0.f), h = fmaxf(dy, 0.f);
            float inter = w * h;
            float uni = (a11 + a2) - inter;
            float ae = ((pw1 + wx) - dx) * ((ph1 + wy) - dy);
            float gi = fmaf(uni, __builtin_amdgcn_rcpf(ae),
                            fmaf(inter, __builtin_amdgcn_rcpf(uni), -1.f));
            if (gi > best1) { best1 = gi; bi1 = m; }
        }
    }

    float box_l = 0.f;
    const int lane = threadIdx.x & 63;

    // anchor 0: emit
    {
        bool pos = (n0 < N) && (best0 > IOU_THR);
        if (pos) box_l += 1.f - best0;
        unsigned long long mk = __ballot(pos);
        int cw = __popcll(mk);
        if (cw > 0) {
            int leader = __ffsll(mk) - 1;
            int base = 0;
            if (lane == leader) base = atomicAdd(counter, cw);
            base = __shfl(base, leader);
            if (pos) {
                int pre = __popcll(mk & ((1ull << lane) - 1ull));
                list[base + pre] = ((unsigned)glbl[bi0] << 18) | (unsigned)(b * N + n0);
            }
        }
    }
    // anchor 1: emit
    {
        bool pos = (n1 < N) && (best1 > IOU_THR);
        if (pos) box_l += 1.f - best1;
        unsigned long long mk = __ballot(pos);
        int cw = __popcll(mk);
        if (cw > 0) {
            int leader = __ffsll(mk) - 1;
            int base = 0;
            if (lane == leader) base = atomicAdd(counter, cw);
            base = __shfl(base, leader);
            if (pos) {
                int pre = __popcll(mk & ((1ull << lane) - 1ull));
                list[base + pre] = ((unsigned)glbl[bi1] << 18) | (unsigned)(b * N + n1);
            }
        }
    }

    // reduce box_l: wave then block
    #pragma unroll
    for (int off = 32; off > 0; off >>= 1) box_l += __shfl_down(box_l, off);
    __shared__ float red[4];
    const int wave = threadIdx.x >> 6;
    if (lane == 0) red[wave] = box_l;
    __syncthreads();
    if (threadIdx.x == 0) {
        float s = red[0] + red[1] + red[2] + red[3];
        atomicAdd(&acc[0], (double)s);
    }
}

__global__ __launch_bounds__(256) void yolo_focal_kernel(
    const float* __restrict__ cls_preds,   // [B*N, C]
    const int*   __restrict__ counter,
    const unsigned* __restrict__ list,
    double* __restrict__ acc)              // acc[1]=cls_l
{
    const int cnt = *counter;
    float cls_l = 0.f;
    for (int i = blockIdx.x * blockDim.x + threadIdx.x; i < cnt;
         i += gridDim.x * blockDim.x) {
        unsigned u = list[i];
        int idx = (int)(u & 0x3FFFFu);
        int lbl = (int)(u >> 18);
        const float* xrow = cls_preds + (size_t)idx * NUM_CLASSES;
        float cl = 0.f;
        #pragma unroll 5
        for (int c4 = 0; c4 < NUM_CLASSES / 4; ++c4) {
            float4 xv = reinterpret_cast<const float4*>(xrow)[c4];
            cl += focal_neg(xv.x);
            cl += focal_neg(xv.y);
            cl += focal_neg(xv.z);
            cl += focal_neg(xv.w);
        }
        cl += focal_target_corr(xrow[lbl]);
        cls_l += cl;
    }

    #pragma unroll
    for (int off = 32; off > 0; off >>= 1) cls_l += __shfl_down(cls_l, off);
    __shared__ float red[4];
    const int lane = threadIdx.x & 63;
    const int wave = threadIdx.x >> 6;
    if (lane == 0) red[wave] = cls_l;
    __syncthreads();
    if (threadIdx.x == 0) {
        float s = red[0] + red[1] + red[2] + red[3];
        atomicAdd(&acc[1], (double)s);
    }
}

__global__ void yolo_finalize(const double* __restrict__ acc,
                              const int* __restrict__ counter,
                              float* __restrict__ out) {
    if (threadIdx.x == 0) {
        double npos = (double)(*counter);
        double loss = (5.0 * acc[0] + acc[1]) / fmax(npos, 1.0);
        out[0] = (float)loss;
    }
}

extern "C" void kernel_launch(void* const* d_in, const int* in_sizes, int n_in,
                              void* d_out, int out_size, void* d_ws, size_t ws_size,
                              hipStream_t stream) {
    const float* box_preds = (const float*)d_in[0];
    const float* cls_preds = (const float*)d_in[1];
    const float* gt_boxes  = (const float*)d_in[2];
    const int*   gt_labels = (const int*)d_in[3];

    const int B = in_sizes[3] / M_GT;            // gt_labels is [B,M]
    const int N = in_sizes[0] / (4 * B);         // box_preds is [B,N,4]

    double*   acc     = (double*)d_ws;
    int*      counter = (int*)((char*)d_ws + 16);
    unsigned* list    = (unsigned*)((char*)d_ws + 32);
    float*    out     = (float*)d_out;

    yolo_init_acc<<<1, 64, 0, stream>>>(d_ws);

    dim3 gridA((N + 511) / 512, B);
    yolo_match_kernel<<<gridA, 256, 0, stream>>>(box_preds, gt_boxes, gt_labels,
                                                 acc, counter, list, N);

    yolo_focal_kernel<<<256, 256, 0, stream>>>(cls_preds, counter, list, acc);

    yolo_finalize<<<1, 64, 0, stream>>>(acc, counter, out);
}

// Round 4
// 66.206 us; speedup vs baseline: 2.0566x; 1.3275x over previous
//
#include <hip/hip_runtime.h>
#include <math.h>

#define NUM_CLASSES 80
#define M_GT 128
#define IOU_THR 0.3f

// ws layout: [0,24): double acc[3] = {box_l, cls_l, npos}
__global__ void yolo_init_acc(double* acc) {
    if (threadIdx.x < 3) acc[threadIdx.x] = 0.0;
}

__device__ __forceinline__ float focal_neg(float x) {
    // (1-ALPHA)=0.75, t=0 term: 0.75 * p^2 * (max(x,0)+log1p(exp(-|x|)))
    float ax = fabsf(x);
    float e  = __expf(-ax);
    float s  = 1.f + e;
    float r  = __builtin_amdgcn_rcpf(s);
    float l1p = __logf(s);
    float ce0 = fmaxf(x, 0.f) + l1p;
    float pr  = (x >= 0.f) ? r : e * r;      // sigmoid(x)
    return 0.75f * pr * pr * ce0;
}

__device__ __forceinline__ float focal_target_corr(float x) {
    // replace t=0 term with t=1 term for the target class
    float ax = fabsf(x);
    float e  = __expf(-ax);
    float s  = 1.f + e;
    float r  = __builtin_amdgcn_rcpf(s);
    float l1p = __logf(s);
    float ce0 = fmaxf(x, 0.f) + l1p;
    float pr  = (x >= 0.f) ? r : e * r;
    float om  = 1.f - pr;
    return 0.25f * om * om * (ce0 - x) - 0.75f * pr * pr * ce0;
}

__global__ __launch_bounds__(256) void yolo_fused_kernel(
    const float* __restrict__ box_preds,   // [B,N,4]
    const float* __restrict__ cls_preds,   // [B,N,C]
    const float* __restrict__ gt_boxes,    // [B,M,4]
    const int*   __restrict__ gt_labels,   // [B,M]
    double* __restrict__ acc,              // {box_l, cls_l, npos}
    int N)
{
    const int b   = blockIdx.y;
    const int tid = threadIdx.x;
    const int n   = blockIdx.x * 256 + tid;

    __shared__ float    sarea[M_GT];
    __shared__ int      s_cnt;
    __shared__ unsigned plist[256];
    __shared__ float    redb[4], redc[4];

    // block-uniform GT pointer -> uniform loads in the m-loop (s_load)
    const float4* __restrict__ gt =
        (const float4*)__builtin_assume_aligned(gt_boxes + (size_t)b * M_GT * 4, 16);

    if (tid == 0) s_cnt = 0;
    if (tid < M_GT) {
        float4 g = gt[tid];
        sarea[tid] = (g.z - g.x) * (g.w - g.y);
    }
    __syncthreads();

    float4 p = reinterpret_cast<const float4*>(box_preds + (size_t)b * N * 4)[n];
    const float a1 = (p.z - p.x) * (p.w - p.y);

    float best = -1e30f;
    int   bidx = 0;

    #pragma unroll 4
    for (int m = 0; m < M_GT; ++m) {
        float4 g = gt[m];        // uniform -> SGPRs via s_load_dwordx4
        float a2 = sarea[m];     // broadcast ds_read_b32
        // intersection extents (unclamped)
        float dx = fminf(p.z, g.z) - fmaxf(p.x, g.x);
        float dy = fminf(p.w, g.w) - fmaxf(p.y, g.y);
        // enclosure extents (always >= 0 for valid boxes)
        float ex = fmaxf(p.z, g.z) - fminf(p.x, g.x);
        float ey = fmaxf(p.w, g.w) - fminf(p.y, g.y);
        float w = fmaxf(dx, 0.f), h = fmaxf(dy, 0.f);
        float inter = w * h;
        float uni = (a1 + a2) - inter;
        float ae  = ex * ey;
        float gi = fmaf(uni, __builtin_amdgcn_rcpf(ae),
                        fmaf(inter, __builtin_amdgcn_rcpf(uni), -1.f));
        if (gi > best) { best = gi; bidx = m; }   // strict > keeps first idx (jnp.argmax)
    }

    const int lane = tid & 63;
    const int wave = tid >> 6;

    bool  pos   = (n < N) && (best > IOU_THR);
    float box_l = pos ? (1.f - best) : 0.f;   // elementwise giou == best (same arithmetic)

    // block-level compaction of positives into LDS
    {
        unsigned long long mk = __ballot(pos);
        int cw = __popcll(mk);
        if (cw > 0) {
            int leader = __ffsll(mk) - 1;
            int base = 0;
            if (lane == leader) base = atomicAdd(&s_cnt, cw);
            base = __shfl(base, leader);
            if (pos) {
                int pre = __popcll(mk & ((1ull << lane) - 1ull));
                unsigned lbl = (unsigned)gt_labels[b * M_GT + bidx];
                plist[base + pre] = (lbl << 18) | (unsigned)(b * N + n);
            }
        }
    }
    __syncthreads();

    // focal over the block's compacted positives (~17 avg), all 4 waves
    const int cnt = s_cnt;
    float cls_l = 0.f;
    for (int i = tid; i < cnt; i += 256) {
        unsigned u = plist[i];
        int row = (int)(u & 0x3FFFFu);
        int lbl = (int)(u >> 18);
        const float* xrow = cls_preds + (size_t)row * NUM_CLASSES;
        float cl = 0.f;
        #pragma unroll 5
        for (int c4 = 0; c4 < NUM_CLASSES / 4; ++c4) {
            float4 xv = reinterpret_cast<const float4*>(xrow)[c4];
            cl += focal_neg(xv.x);
            cl += focal_neg(xv.y);
            cl += focal_neg(xv.z);
            cl += focal_neg(xv.w);
        }
        cl += focal_target_corr(xrow[lbl]);
        cls_l += cl;
    }

    // reductions: wave shfl, then block via LDS
    #pragma unroll
    for (int off = 32; off > 0; off >>= 1) {
        box_l += __shfl_down(box_l, off);
        cls_l += __shfl_down(cls_l, off);
    }
    if (lane == 0) { redb[wave] = box_l; redc[wave] = cls_l; }
    __syncthreads();
    if (tid == 0) {
        float b0 = redb[0] + redb[1] + redb[2] + redb[3];
        float c0 = redc[0] + redc[1] + redc[2] + redc[3];
        atomicAdd(&acc[0], (double)b0);
        atomicAdd(&acc[1], (double)c0);
        atomicAdd(&acc[2], (double)cnt);
    }
}

__global__ void yolo_finalize(const double* __restrict__ acc, float* __restrict__ out) {
    if (threadIdx.x == 0) {
        double loss = (5.0 * acc[0] + acc[1]) / fmax(acc[2], 1.0);
        out[0] = (float)loss;
    }
}

extern "C" void kernel_launch(void* const* d_in, const int* in_sizes, int n_in,
                              void* d_out, int out_size, void* d_ws, size_t ws_size,
                              hipStream_t stream) {
    const float* box_preds = (const float*)d_in[0];
    const float* cls_preds = (const float*)d_in[1];
    const float* gt_boxes  = (const float*)d_in[2];
    const int*   gt_labels = (const int*)d_in[3];

    const int B = in_sizes[3] / M_GT;            // gt_labels is [B,M]
    const int N = in_sizes[0] / (4 * B);         // box_preds is [B,N,4]

    double* acc = (double*)d_ws;
    float*  out = (float*)d_out;

    yolo_init_acc<<<1, 64, 0, stream>>>(acc);

    dim3 grid((N + 255) / 256, B);
    yolo_fused_kernel<<<grid, 256, 0, stream>>>(box_preds, cls_preds, gt_boxes,
                                                gt_labels, acc, N);

    yolo_finalize<<<1, 64, 0, stream>>>(acc, out);
}